// Round 7
// baseline (149.009 us; speedup 1.0000x reference)
//
#include <hip/hip_runtime.h>

#define TT 8
#define NN 2048
#define SS 8192
#define MM (NN * SS)   // 16777216 elements

// Bernoulli integer thresholds: p * 2^23 (all probabilities are dyadic k/128)
#define TH_CAP10  655360u    // 10/128 * 2^23  (ucapture, uminus)
#define TH_SEARCH 65536u     //  1/128 * 2^23
#define TH_BACK   6291456u   // 96/128 * 2^23
#define TH_MIN    262144u    //  4/128 * 2^23

#define WPB         2                       // waves per block (128 threads)
#define NBLOCKS     1024                    // 4 blocks/CU (LDS-capped)
#define TOTAL_WAVES (NBLOCKS * WPB)         // 2048
#define EPT         4                       // elements per lane per tile
#define TILE_ELEMS  (64 * EPT)              // 256 elements per wave-tile
#define NTILES      (MM / TILE_ELEMS)       // 65536
#define ITERS       (NTILES / TOTAL_WAVES)  // 32
#define NPLANES     9                       // 8 spike planes + 1 W plane

typedef int   __attribute__((ext_vector_type(4))) intx4;
typedef float __attribute__((ext_vector_type(4))) floatx4;
typedef unsigned __attribute__((ext_vector_type(4))) uintx4;

// 4 branch-config rows x 8 words: {ka0,ka1, kb0,kb1, kc0,kc1, thB, sgn_bits}
struct Tbl { unsigned v[32]; };

__host__ __device__ __forceinline__ void tf2x32(unsigned k0, unsigned k1,
                                                unsigned x0, unsigned x1,
                                                unsigned& o0, unsigned& o1) {
  const unsigned ks2 = k0 ^ k1 ^ 0x1BD11BDAu;
  x0 += k0; x1 += k1;
#define TFR(r) { x0 += x1; x1 = (x1 << (r)) | (x1 >> (32 - (r))); x1 ^= x0; }
  TFR(13) TFR(15) TFR(26) TFR(6)
  x0 += k1;  x1 += ks2 + 1u;
  TFR(17) TFR(29) TFR(16) TFR(24)
  x0 += ks2; x1 += k0 + 2u;
  TFR(13) TFR(15) TFR(26) TFR(6)
  x0 += k0;  x1 += k1 + 3u;
  TFR(17) TFR(29) TFR(16) TFR(24)
  x0 += k1;  x1 += ks2 + 4u;
  TFR(13) TFR(15) TFR(26) TFR(6)
  x0 += ks2; x1 += k0 + 5u;
#undef TFR
  o0 = x0; o1 = x1;
}

// Counted vmcnt wait. sched_barrier(0) stops hipcc hoisting register-only
// consumers above the wait (guide rule #18).
#define VMWAIT(N) do {                                                  \
    asm volatile("s_waitcnt vmcnt(" #N ")" ::: "memory");               \
    __builtin_amdgcn_sched_barrier(0);                                  \
  } while (0)

__global__ __launch_bounds__(128) void ModSTDP_58823872086838_kernel(
    const int* __restrict__ inS,    // [T, N, S] int32 0/1
    const int* __restrict__ outS,   // [T, N]    int32 0/1
    const float* __restrict__ W,    // [N, S]
    float* __restrict__ out,        // [N, S]
    Tbl tb)
{
  // Per-wave-private staging ring: [wave][buf][plane][256 ints] = 36 KB.
  // Total LDS 39 KB < 64 KB: keeps EVERY LDS-DMA destination inside the
  // first 64 KiB (R6 failed with a 72 KB ring — working theory: the LDS-DMA
  // path addresses only a 64 KiB window; targets beyond it wrap/corrupt).
  __shared__ __align__(16) int ring[WPB][2][NPLANES][TILE_ELEMS];
  __shared__ unsigned char osum_s[NN];       // 2 KB: per-row output counts
  __shared__ __align__(16) unsigned tbl[32];

  if (threadIdx.x < 32) tbl[threadIdx.x] = tb.v[threadIdx.x];
  {
    const int r0 = threadIdx.x * 16;         // 128 threads x 16 rows = 2048
    int acc[16];
#pragma unroll
    for (int k = 0; k < 16; ++k) acc[k] = 0;
#pragma unroll
    for (int t = 0; t < TT; ++t) {
#pragma unroll
      for (int k = 0; k < 16; ++k) acc[k] += outS[t * NN + r0 + k];
    }
#pragma unroll
    for (int k = 0; k < 16; ++k) osum_s[r0 + k] = (unsigned char)acc[k];
  }
  __syncthreads();   // all prologue loads consumed: vmcnt=0 before counting

  const unsigned wid  = threadIdx.x >> 6;
  const unsigned lane = threadIdx.x & 63;
  unsigned tile = blockIdx.x * WPB + wid;

#define STAGE(T_, B_)                                                        \
  do {                                                                      \
    const unsigned eb_ = (T_) * TILE_ELEMS + lane * EPT;                    \
    _Pragma("unroll")                                                       \
    for (int t_ = 0; t_ < TT; ++t_) {                                       \
      const int* src_ = inS + (size_t)t_ * MM + eb_;                        \
      __builtin_amdgcn_global_load_lds(                                     \
          (const __attribute__((address_space(1))) void*)src_,              \
          (__attribute__((address_space(3))) void*)&ring[wid][B_][t_][lane * EPT], \
          16, 0, 0);                                                        \
    }                                                                       \
    const int* wsrc_ = (const int*)W + eb_;                                 \
    __builtin_amdgcn_global_load_lds(                                       \
        (const __attribute__((address_space(1))) void*)wsrc_,               \
        (__attribute__((address_space(3))) void*)&ring[wid][B_][TT][lane * EPT], \
        16, 0, 0);                                                          \
  } while (0)

  STAGE(tile, 0);

  unsigned buf = 0;
#pragma unroll 1
  for (int it = 0; it < ITERS; ++it) {
    const unsigned nextTile = tile + TOTAL_WAVES;
    if (it + 1 < ITERS) {
      STAGE(nextTile, buf ^ 1);
      // Queue (oldest->newest): [stage_it(9), store_{it-1}(<=1), stage_{it+1}(9)].
      // The 10 oldest always include all of stage_it regardless of where the
      // compiler placed the store, so vmcnt(9) guarantees buf's data landed.
      VMWAIT(9);
    } else {
      VMWAIT(0);
    }

    const unsigned ebase = tile * TILE_ELEMS + lane * EPT;
    const int o = (int)osum_s[tile >> 5];    // row = (tile*256)>>13
    const bool outF = o > 0;

    intx4 sv[TT];
#pragma unroll
    for (int t = 0; t < TT; ++t)
      sv[t] = *(const intx4*)&ring[wid][buf][t][lane * EPT];
    const floatx4 w4 = *(const floatx4*)&ring[wid][buf][TT][lane * EPT];

    int cnt[EPT] = {0, 0, 0, 0};
#pragma unroll
    for (int t = 0; t < TT; ++t) {
#pragma unroll
      for (int e = 0; e < EPT; ++e) cnt[e] += sv[t][e];
    }

    float res[EPT];
#pragma unroll
    for (int e = 0; e < EPT; ++e) {
      const unsigned j = ebase + (unsigned)e;
      const float w = fminf(fmaxf(w4[e], 0.0f), 8.0f);
      const int c = cnt[e];
      const bool inF = c > 0;
      const bool active = inF | outF;
      // branch index: 0=capture 1=minus 2=search 3=backoff
      // (in_t <= out_t) <=> (8-c <= 8-o) <=> (c >= o)
      const unsigned idx = inF ? (outF ? ((c >= o) ? 0u : 1u) : 2u) : 3u;

      const uintx4 r0 = *reinterpret_cast<const uintx4*>(tbl + (idx << 3));
      const uintx4 r1 = *reinterpret_cast<const uintx4*>(tbl + (idx << 3) + 4);
      const unsigned ka0 = r0.x, ka1 = r0.y, kb0 = r0.z, kb1 = r0.w;
      const unsigned kc0 = r1.x, kc1 = r1.y, thB = r1.z;
      const float sgn = __uint_as_float(r1.w);

      // p_plus / p_minus exactly as XLA (no FMA contraction)
      const float wn = w * 0.125f;
      const float pp = __fmul_rn(wn, __fsub_rn(2.0f, wn));
      const float pm = __fmul_rn(__fsub_rn(1.0f, wn), __fadd_rn(1.0f, wn));
      const float pA = (idx & 1u) ? pm : pp;   // odd rows use fminus

      unsigned a0, a1, b0, b1, c0, c1;
      tf2x32(ka0, ka1, 0u, j, a0, a1);
      const unsigned bitsA = a0 ^ a1;          // partitionable: x0 ^ x1
      const float u = __uint_as_float((bitsA >> 9) | 0x3f800000u) - 1.0f;
      const bool fab = u < pA;

      tf2x32(kb0, kb1, 0u, j, b0, b1);
      const bool gate = (((b0 ^ b1) >> 9) < thB);

      tf2x32(kc0, kc1, 0u, j, c0, c1);
      const bool um = (((c0 ^ c1) >> 9) < TH_MIN);

      const bool doit = active & gate & (fab | um);
      res[e] = doit ? __fadd_rn(w, sgn) : w;
    }

    floatx4 r;
    r.x = res[0]; r.y = res[1]; r.z = res[2]; r.w = res[3];
    __builtin_nontemporal_store(r, reinterpret_cast<floatx4*>(out + ebase));

    tile = nextTile;
    buf ^= 1;
  }
#undef STAGE
}

extern "C" void kernel_launch(void* const* d_in, const int* in_sizes, int n_in,
                              void* d_out, int out_size, void* d_ws, size_t ws_size,
                              hipStream_t stream) {
  const int*   inS  = (const int*)d_in[0];
  const int*   outS = (const int*)d_in[1];
  const float* W    = (const float*)d_in[2];
  float*       out  = (float*)d_out;

  // Host-side key derivation (pure arithmetic — graph-capture safe).
  // jax.random.key(42) -> (0, 42). Fold-like split (threefry_partitionable):
  // rk[i] = threefry(key, (0, i));  k7{a,b,c} = threefry(rk7, (0, {0,1,2}))
  unsigned kp[20];
  {
    unsigned rk[16];
    for (unsigned i = 0; i < 8; ++i) {
      unsigned o0, o1;
      tf2x32(0u, 42u, 0u, i, o0, o1);
      rk[2 * i] = o0; rk[2 * i + 1] = o1;
    }
    for (int i = 0; i < 14; ++i) kp[i] = rk[i];      // rk0..rk6
    for (unsigned i = 0; i < 3; ++i) {
      unsigned o0, o1;
      tf2x32(rk[14], rk[15], 0u, i, o0, o1);
      kp[14 + 2 * i] = o0; kp[15 + 2 * i] = o1;
    }
  }

  // Branch-config table rows: {ka0,ka1, kb0,kb1, kc0,kc1, thB, sgn}
  Tbl tb;
  unsigned* v = tb.v;
  // row 0: capture  — fplus, ucapture, umin1, +1
  v[0] = kp[0];  v[1] = kp[1];  v[2] = kp[4];   v[3] = kp[5];
  v[4] = kp[12]; v[5] = kp[13]; v[6] = TH_CAP10; v[7] = 0x3f800000u;
  // row 1: minus    — fminus, uminus, umin2, -1
  v[8] = kp[2];  v[9] = kp[3];  v[10] = kp[6];  v[11] = kp[7];
  v[12] = kp[14]; v[13] = kp[15]; v[14] = TH_CAP10; v[15] = 0xbf800000u;
  // row 2: search   — fplus, usearch, umin3, +1
  v[16] = kp[0]; v[17] = kp[1]; v[18] = kp[8];  v[19] = kp[9];
  v[20] = kp[16]; v[21] = kp[17]; v[22] = TH_SEARCH; v[23] = 0x3f800000u;
  // row 3: backoff  — fminus, ubackoff, umin4, -1
  v[24] = kp[2]; v[25] = kp[3]; v[26] = kp[10]; v[27] = kp[11];
  v[28] = kp[18]; v[29] = kp[19]; v[30] = TH_BACK; v[31] = 0xbf800000u;

  ModSTDP_58823872086838_kernel<<<dim3(NBLOCKS), dim3(128), 0, stream>>>(
      inS, outS, W, out, tb);
}